// Round 5
// baseline (608.850 us; speedup 1.0000x reference)
//
#include <hip/hip_runtime.h>
#include <stdint.h>

// SparseLinear: out[m][n] = sum_k x[m][k] * W[n][k] * mask[n][k]
// M = B*S = 8192, N = 4096, K = 4096, fp32 in/out, bf16-tolerance check.
//
// R7: occupancy attack. R3/R5/R6 all ~240us @ MfmaUtil 49% -> the 1-block/CU
// lockstep structure serializes LDS-drain + MFMA + barriers (measured phase
// 1115 cy vs 621 cy MFMA work); no schedule variant moved it. Fix = 2
// independent blocks/CU so one block's MFMA region overlaps the other's
// LDS/barrier region (m114 implicit overlap; m103's 912TF came from 3
// blocks/CU). Limiters cut: LDS 72 KB/block (<80), regs <=128/wave
// (m69 cliff) -> per-wave output 64x64 (acc 64 regs).
//   BM=256 BN=128 BK=32, 8 waves (4Mx2N), grid 1024 (4/CU, 2 resident).
//   LDS: A 3 bufs x 16 KB, B 3 bufs x 8 KB (triple buffer).
//   Per K-tile: 2 phases; P1 {rd a0-3,b0-1 (6xb128), stage A(t+2) 2x
//   gload_lds, bar, 8 MFMA mi0-3 x ni0-1, bar}; P2 {rd b2-3, stage B(t+2),
//   bar, 8 MFMA mi0-3 x ni2-3, vmcnt(3), bar}.
//   vmcnt ledger: 3 loads/K-tile; at P2-end outstanding = t+1(3) + t+2(3);
//   vmcnt(3) retires t+1 (staged one full K-tile earlier, ~2000 cy cover),
//   t+2 stays in flight. WAR: t+2 -> buf (t+2)%3 = buf of t-1, whose last
//   read was t-1's P2, >=2 barriers before stage issue. Cross-wave: each
//   wave waits own vmcnt before s_barrier -> whole tile visible after.
// Verified idioms unchanged: 16x16x32 frag layout (m/n=lane&15,
// k=(lane>>4)*8+i), C/D (col=lane&15,row=(lane>>4)*4+reg), chunk-XOR
// swizzle (key row&3, 4 chunks/row), linear gload dest + pre-swizzled
// source col, bijective XCD swizzle (1024%8==0).

static constexpr int Mdim = 8192;
static constexpr int Ndim = 4096;
static constexpr int Kdim = 4096;
static constexpr int BM = 256;
static constexpr int BN = 128;
static constexpr int BK = 32;
static constexpr int NT = Kdim / BK;  // 128 K-tiles

typedef __attribute__((ext_vector_type(8))) short short8;
typedef __attribute__((ext_vector_type(4))) float float4v;
typedef __attribute__((ext_vector_type(4))) float f32x4;
typedef __attribute__((ext_vector_type(4))) int int4v;
typedef __attribute__((ext_vector_type(8))) unsigned short ushort8;

__device__ __forceinline__ unsigned short f32_to_bf16(float f) {
  union { float f; uint32_t u; } c; c.f = f;
  uint32_t u = c.u;
  u += 0x7fffu + ((u >> 16) & 1u);   // round-to-nearest-even (no NaNs in data)
  return (unsigned short)(u >> 16);
}

// ---------------------------------------------------------------------------
// Mask element-width detection. numpy bool_ = 1 byte; int32/float32 promotion
// would zero byte positions ==1 (mod 4). 10% density over 1M positions ->
// ~105k hits for byte layout, exactly 0 for 4-byte layouts.
// ---------------------------------------------------------------------------
__global__ void detect_mask_kernel(const unsigned char* __restrict__ m, int* __restrict__ flag) {
  int found = 0;
  const int total = 1 << 20;  // scan first 4 MiB
  for (int p = blockIdx.x * blockDim.x + threadIdx.x; p < total;
       p += gridDim.x * blockDim.x)
    found |= (m[4 * p + 1] != 0);
  if (__any(found) && (threadIdx.x & 63) == 0) atomicOr(flag, 1);
}

// x fp32 -> bf16, 8 elements/thread (two 16B loads, one 16B store)
__global__ void cvt_x_kernel(const float* __restrict__ x, unsigned short* __restrict__ o) {
  long i = (blockIdx.x * (long)blockDim.x + threadIdx.x) * 8;
  float4v v0 = *(const float4v*)(x + i);
  float4v v1 = *(const float4v*)(x + i + 4);
  ushort8 r;
  r[0] = f32_to_bf16(v0[0]); r[1] = f32_to_bf16(v0[1]);
  r[2] = f32_to_bf16(v0[2]); r[3] = f32_to_bf16(v0[3]);
  r[4] = f32_to_bf16(v1[0]); r[5] = f32_to_bf16(v1[1]);
  r[6] = f32_to_bf16(v1[2]); r[7] = f32_to_bf16(v1[3]);
  *(ushort8*)(o + i) = r;
}

// W fp32 * mask -> bf16, 8 elements/thread; mask layout chosen by *flag
__global__ void cvt_w_kernel(const float* __restrict__ w, const unsigned char* __restrict__ mraw,
                             const int* __restrict__ flag, unsigned short* __restrict__ o) {
  long i = (blockIdx.x * (long)blockDim.x + threadIdx.x) * 8;
  float4v w0 = *(const float4v*)(w + i);
  float4v w1 = *(const float4v*)(w + i + 4);
  int m[8];
  if (*flag) {  // 1-byte elements
    unsigned long long mb = *(const unsigned long long*)(mraw + i);
#pragma unroll
    for (int j = 0; j < 8; ++j) m[j] = ((mb >> (8 * j)) & 0xffull) != 0;
  } else {      // 4-byte elements (int32 0/1 or float32 0.0/1.0 — both: nonzero word)
    int4v a = *(const int4v*)((const int*)mraw + i);
    int4v b = *(const int4v*)((const int*)mraw + i + 4);
#pragma unroll
    for (int j = 0; j < 4; ++j) { m[j] = a[j] != 0; m[4 + j] = b[j] != 0; }
  }
  ushort8 r;
  r[0] = f32_to_bf16(m[0] ? w0[0] : 0.0f);
  r[1] = f32_to_bf16(m[1] ? w0[1] : 0.0f);
  r[2] = f32_to_bf16(m[2] ? w0[2] : 0.0f);
  r[3] = f32_to_bf16(m[3] ? w0[3] : 0.0f);
  r[4] = f32_to_bf16(m[4] ? w1[0] : 0.0f);
  r[5] = f32_to_bf16(m[5] ? w1[1] : 0.0f);
  r[6] = f32_to_bf16(m[6] ? w1[2] : 0.0f);
  r[7] = f32_to_bf16(m[7] ? w1[3] : 0.0f);
  *(ushort8*)(o + i) = r;
}

// ---------------------------------------------------------------------------
// GEMM helpers
// ---------------------------------------------------------------------------

__device__ __forceinline__ void gload16(const unsigned short* g, char* l) {
  __builtin_amdgcn_global_load_lds((const __attribute__((address_space(1))) void*)g,
                                   (__attribute__((address_space(3))) void*)l, 16, 0, 0);
}

__device__ __forceinline__ void phase_pre() {
  __builtin_amdgcn_s_barrier();
  __builtin_amdgcn_s_setprio(1);
}

__device__ __forceinline__ void phase_post() {
  __builtin_amdgcn_s_setprio(0);
  __builtin_amdgcn_s_barrier();
}

__device__ __forceinline__ void phase_post_vm() {
  __builtin_amdgcn_s_setprio(0);
  asm volatile("s_waitcnt vmcnt(3)" ::: "memory");  // counted: tile t+2 in flight
  __builtin_amdgcn_s_barrier();
}

// ---------------------------------------------------------------------------
// bf16 MFMA GEMM, B^T form: O[m][n] = sum_k X[m][k]*W[n][k].
// 512 threads = 8 waves (4M x 2N); per-wave 64x64 via 16x16x32 MFMA.
// A/B frag layout: m/n = lane&15, k = (lane>>4)*8 + i.
// C/D layout (m89-verified): col = lane&15, row = (lane>>4)*4 + reg.
// LDS rows: A tile [256][32] (64B rows), B tile [128][32]; chunk (16B) XOR
// swizzle: LDS chunk j of row r holds global chunk j ^ (r&3).
// ---------------------------------------------------------------------------
__global__ __launch_bounds__(512, 4) void gemm_bt_kernel(const unsigned short* __restrict__ X,
                                                         const unsigned short* __restrict__ W,
                                                         float* __restrict__ O) {
  __shared__ __align__(16) char lds[73728];
  char* sA = lds;            // 3 bufs x 16384 (A: 256 rows x 64 B)
  char* sB = lds + 49152;    // 3 bufs x 8192  (B: 128 rows x 64 B)

  const int tid = threadIdx.x;
  const int lane = tid & 63;
  const int wave = tid >> 6;
  const int wm = wave >> 1;        // 0..3 : M strip (rows wm*64..+64)
  const int wn = wave & 1;         // 0..1 : N strip (cols wn*64..+64)

  // Bijective XCD swizzle: 1024 blocks, 8 XCDs -> 128 contiguous ids per XCD.
  const int bid = blockIdx.x;
  const int id = (bid & 7) * 128 + (bid >> 3);
  const int tm = id >> 5;          // 0..31
  const int tn = id & 31;          // 0..31
  const int row0 = tm * BM;
  const int col0 = tn * BN;

  // staging per-thread constants: thread covers (row sr, 16B chunk tid&3);
  // source col pre-swizzled so linear LDS dest yields chunk^(row&3) layout.
  const int sr = tid >> 2;                         // 0..127
  const int sc = ((tid & 3) ^ (sr & 3)) * 8;       // elems
  const int l0 = tid * 16;                         // linear LDS byte offset

  const unsigned short* gA = X + (size_t)(row0 + sr) * Kdim + sc;   // rows 0-127
  const unsigned short* gB = W + (size_t)(col0 + sr) * Kdim + sc;   // rows 0-127

  // ds_read per-thread constants
  const int arow = lane & 15;
  const int kg = lane >> 4;                        // 0..3
  const int cb = (kg ^ (lane & 3)) * 16;           // swizzled chunk byte offset
  const int abase = (wm * 64 + arow) * 64 + cb;    // + mi*1024
  const int bbase = (wn * 64 + arow) * 64 + cb;    // + ni*1024

  f32x4 acc[4][4];
#pragma unroll
  for (int i = 0; i < 4; ++i)
#pragma unroll
    for (int j = 0; j < 4; ++j)
#pragma unroll
      for (int r = 0; r < 4; ++r) acc[i][j][r] = 0.f;

  short8 a[4], b[4];

  // Prologue: tile 0 -> buf0, tile 1 -> buf1 (3 loads/thread each)
  gload16(gA, sA + l0);                                 // t0 A.h0
  gload16(gA + (size_t)128 * Kdim, sA + 8192 + l0);     // t0 A.h1
  gload16(gB, sB + l0);                                 // t0 B
  gload16(gA + BK, sA + 16384 + l0);                    // t1 A.h0
  gload16(gA + (size_t)128 * Kdim + BK, sA + 24576 + l0);  // t1 A.h1
  gload16(gB + BK, sB + 8192 + l0);                     // t1 B
  asm volatile("s_waitcnt vmcnt(3)" ::: "memory");      // t0 landed; t1 in flight
  __builtin_amdgcn_s_barrier();

  int rc = 0;  // buffer of tile t; stage buf = (rc+2)%3
#pragma unroll 1
  for (int t = 0; t < NT; ++t) {
    const int sb = (rc == 0) ? 2 : rc - 1;             // (rc+2)%3
    const int ks = ((t + 2) & (NT - 1)) * BK;          // wrapped tail: staged, never read
    const char* pA = sA + rc * 16384;
    const char* pB = sB + rc * 8192;
    char* qA = sA + sb * 16384;
    char* qB = sB + sb * 8192;

    // ---- P1: reads a0-3, b0-1; stage A(t+2); MFMA mi0-3 x ni0-1 ----
#pragma unroll
    for (int mi = 0; mi < 4; ++mi)
      a[mi] = *(const short8*)(pA + abase + mi * 1024);
#pragma unroll
    for (int ni = 0; ni < 2; ++ni)
      b[ni] = *(const short8*)(pB + bbase + ni * 1024);
    gload16(gA + ks, qA + l0);                          // A(t+2).h0
    gload16(gA + (size_t)128 * Kdim + ks, qA + 8192 + l0);  // A(t+2).h1
    phase_pre();
#pragma unroll
    for (int mi = 0; mi < 4; ++mi)
#pragma unroll
      for (int ni = 0; ni < 2; ++ni)
        acc[mi][ni] = __builtin_amdgcn_mfma_f32_16x16x32_bf16(a[mi], b[ni], acc[mi][ni], 0, 0, 0);
    phase_post();

    // ---- P2: reads b2-3; stage B(t+2); MFMA mi0-3 x ni2-3 ----
#pragma unroll
    for (int ni = 2; ni < 4; ++ni)
      b[ni] = *(const short8*)(pB + bbase + ni * 1024);
    gload16(gB + ks, qB + l0);                          // B(t+2)
    phase_pre();
#pragma unroll
    for (int mi = 0; mi < 4; ++mi)
#pragma unroll
      for (int ni = 2; ni < 4; ++ni)
        acc[mi][ni] = __builtin_amdgcn_mfma_f32_16x16x32_bf16(a[mi], b[ni], acc[mi][ni], 0, 0, 0);
    phase_post_vm();                                    // tile t+1 landed

    rc = (rc == 2) ? 0 : rc + 1;
  }

  // Epilogue: C/D row = (lane>>4)*4 + reg, col = lane&15
  const int orow0 = row0 + wm * 64 + kg * 4;
  const int ocol0 = col0 + wn * 64 + arow;
#pragma unroll
  for (int mi = 0; mi < 4; ++mi)
#pragma unroll
    for (int ni = 0; ni < 4; ++ni)
#pragma unroll
      for (int r = 0; r < 4; ++r)
        O[(size_t)(orow0 + mi * 16 + r) * Ndim + ocol0 + ni * 16] = acc[mi][ni][r];
}

// ---------------------------------------------------------------------------
// Fallback (only if ws too small for bf16 staging): fp32 LDS-tiled GEMM.
// ---------------------------------------------------------------------------
__global__ void gemm_fallback_kernel(const float* __restrict__ X, const float* __restrict__ Wt,
                                     const unsigned char* __restrict__ mraw,
                                     const int* __restrict__ flag, float* __restrict__ O) {
  __shared__ float sX[16][17];
  __shared__ float sW[16][17];
  const int tx = threadIdx.x & 15;
  const int ty = threadIdx.x >> 4;
  const long row = blockIdx.y * 16 + ty;
  const long colblock = blockIdx.x * 16;
  const int byteLayout = *flag;
  float acc = 0.f;
  for (int k0 = 0; k0 < Kdim; k0 += 16) {
    sX[ty][tx] = X[row * Kdim + k0 + tx];
    const long wi = (colblock + ty) * (long)Kdim + k0 + tx;
    const int mv = byteLayout ? (mraw[wi] != 0) : (((const int*)mraw)[wi] != 0);
    sW[ty][tx] = mv ? Wt[wi] : 0.f;
    __syncthreads();
#pragma unroll
    for (int k = 0; k < 16; ++k) acc += sX[ty][k] * sW[tx][k];
    __syncthreads();
  }
  O[row * Ndim + colblock + tx] = acc;
}

extern "C" void kernel_launch(void* const* d_in, const int* in_sizes, int n_in,
                              void* d_out, int out_size, void* d_ws, size_t ws_size,
                              hipStream_t stream) {
  const float* x = (const float*)d_in[0];               // [8192, 4096] fp32
  const float* w = (const float*)d_in[1];               // [4096, 4096] fp32
  const unsigned char* mask = (const unsigned char*)d_in[2];  // bool (layout detected)
  float* out = (float*)d_out;                           // [8192, 4096] fp32

  const size_t xb_off = 0;
  const size_t wb_off = (size_t)Mdim * Kdim * 2;             // 67,108,864
  const size_t flag_off = wb_off + (size_t)Ndim * Kdim * 2;  // 100,663,296
  const size_t needed = flag_off + 16;

  if (ws_size >= needed) {
    unsigned short* xb = (unsigned short*)((char*)d_ws + xb_off);
    unsigned short* wb = (unsigned short*)((char*)d_ws + wb_off);
    int* flag = (int*)((char*)d_ws + flag_off);

    hipMemsetAsync(flag, 0, sizeof(int), stream);
    detect_mask_kernel<<<64, 256, 0, stream>>>(mask, flag);
    cvt_x_kernel<<<(int)(((long)Mdim * Kdim / 8) / 256), 256, 0, stream>>>(x, xb);
    cvt_w_kernel<<<(int)(((long)Ndim * Kdim / 8) / 256), 256, 0, stream>>>(w, mask, flag, wb);
    gemm_bt_kernel<<<(Mdim / BM) * (Ndim / BN), 512, 0, stream>>>(xb, wb, out);
  } else {
    int* flag = (int*)d_ws;
    hipMemsetAsync(flag, 0, sizeof(int), stream);
    detect_mask_kernel<<<64, 256, 0, stream>>>(mask, flag);
    dim3 grid(Ndim / 16, Mdim / 16);
    gemm_fallback_kernel<<<grid, 256, 0, stream>>>(x, w, mask, flag, out);
  }
}

// Round 6
// 514.268 us; speedup vs baseline: 1.1839x; 1.1839x over previous
//
#include <hip/hip_runtime.h>
#include <stdint.h>

// SparseLinear: out[m][n] = sum_k x[m][k] * W[n][k] * mask[n][k]
// M = B*S = 8192, N = 4096, K = 4096, fp32 in/out, bf16-tolerance check.
//
// R8: (a) GEMM reverted byte-identical to R6 (238us, MfmaUtil 49, 3x verified;
// R7's 256x128/BK32 experiment regressed to 300us: LDS/MFMA ratio 2.4 ->
// LDS-BW-bound 41% ceiling + structural 4-way conflicts at 64B rows).
// (b) Prep pipeline collapsed 4 dispatches -> 1: fused grid-stride kernel
// does x->bf16 and (w*mask)->bf16; mask element-width detection is per-wave
// (512 word-byte1 tests in mask[0..8MB): byte layout -> ~51 expected hits,
// P(miss) = 0.9^512 = 4e-24/wave; int32/fp32 word layouts -> byte1 of
// 0/1/1.0f is deterministically 0). Removes memset + detect dispatch + flag.
//
// GEMM structure (R6): 256x256 tile, BK=64, 8 waves (2M x 4N), per-wave
// 128x64 via 16x16x32 MFMA; LDS 160 KiB: A 3 tile-bufs x 32K, B 2 x 32K;
// 8 phases / 2 K-tiles; one half-tile staged per phase via global_load_lds;
// vmcnt(8) at P4/P8 only (4 half-tiles in flight, never drained); chunk-XOR
// swizzle (chunk ^= row&7) via pre-swizzled global source + swizzled
// ds_read addr (conflicts = 0 measured); bijective XCD swizzle.

static constexpr int Mdim = 8192;
static constexpr int Ndim = 4096;
static constexpr int Kdim = 4096;
static constexpr int BM = 256;
static constexpr int BN = 256;
static constexpr int BK = 64;
static constexpr int NT = Kdim / BK;  // 64 K-tiles

typedef __attribute__((ext_vector_type(8))) short short8;
typedef __attribute__((ext_vector_type(4))) float float4v;
typedef __attribute__((ext_vector_type(4))) float f32x4;
typedef __attribute__((ext_vector_type(4))) int int4v;
typedef __attribute__((ext_vector_type(8))) unsigned short ushort8;

__device__ __forceinline__ unsigned short f32_to_bf16(float f) {
  union { float f; uint32_t u; } c; c.f = f;
  uint32_t u = c.u;
  u += 0x7fffu + ((u >> 16) & 1u);   // round-to-nearest-even (no NaNs in data)
  return (unsigned short)(u >> 16);
}

// ---------------------------------------------------------------------------
// Fused prep: x fp32 -> bf16 AND w*mask fp32 -> bf16, one grid-stride kernel.
// Mask layout sniffed per wave: numpy bool_ = 1 byte/elem; int32/fp32 = 4.
// Word-view byte1 (bits 8-15) is nonzero only under byte layout (mask values
// 0/1 land at byte positions 1 mod 4); int 1 and fp32 1.0 (0x3F800000) have
// byte1 == 0. Sniff window stays inside mask[0 .. 8 MiB) (mask >= 16 MiB).
// ---------------------------------------------------------------------------
__global__ __launch_bounds__(256) void prep_kernel(const float* __restrict__ x,
                                                   const float* __restrict__ w,
                                                   const unsigned char* __restrict__ mraw,
                                                   unsigned short* __restrict__ xb,
                                                   unsigned short* __restrict__ wb) {
  const long XS = (long)Mdim * Kdim / 8;   // 4,194,304 x-slots (8 elems each)
  const long WS = (long)Ndim * Kdim / 8;   // 2,097,152 w-slots
  const long tid0 = blockIdx.x * (long)blockDim.x + threadIdx.x;
  const long stride = gridDim.x * (long)blockDim.x;

  // per-wave mask-layout sniff: 8 words/lane, 512 tests/wave, coalesced 2KB
  const long wid = tid0 >> 6;
  const int lane = (int)(tid0 & 63);
  const int* mw = (const int*)mraw;
  const long sbase = (wid & 4095) * 512 + lane * 8;   // word index < 2,097,152 (8 MiB)
  int4v s0 = *(const int4v*)(mw + sbase);
  int4v s1 = *(const int4v*)(mw + sbase + 4);
  int found = 0;
#pragma unroll
  for (int j = 0; j < 4; ++j) found |= ((s0[j] >> 8) & 0xff) | ((s1[j] >> 8) & 0xff);
  const bool byteLayout = __any(found != 0);

  for (long s = tid0; s < XS + WS; s += stride) {
    if (s < XS) {
      const long i = s * 8;
      float4v v0 = *(const float4v*)(x + i);
      float4v v1 = *(const float4v*)(x + i + 4);
      ushort8 r;
      r[0] = f32_to_bf16(v0[0]); r[1] = f32_to_bf16(v0[1]);
      r[2] = f32_to_bf16(v0[2]); r[3] = f32_to_bf16(v0[3]);
      r[4] = f32_to_bf16(v1[0]); r[5] = f32_to_bf16(v1[1]);
      r[6] = f32_to_bf16(v1[2]); r[7] = f32_to_bf16(v1[3]);
      *(ushort8*)(xb + i) = r;
    } else {
      const long i = (s - XS) * 8;
      float4v w0 = *(const float4v*)(w + i);
      float4v w1 = *(const float4v*)(w + i + 4);
      int m[8];
      if (byteLayout) {  // 1-byte elements
        unsigned long long mb = *(const unsigned long long*)(mraw + i);
#pragma unroll
        for (int j = 0; j < 8; ++j) m[j] = ((mb >> (8 * j)) & 0xffull) != 0;
      } else {           // 4-byte elements (int32 0/1 or fp32 0.0/1.0)
        int4v a = *(const int4v*)((const int*)mraw + i);
        int4v b = *(const int4v*)((const int*)mraw + i + 4);
#pragma unroll
        for (int j = 0; j < 4; ++j) { m[j] = a[j] != 0; m[4 + j] = b[j] != 0; }
      }
      ushort8 r;
      r[0] = f32_to_bf16(m[0] ? w0[0] : 0.0f);
      r[1] = f32_to_bf16(m[1] ? w0[1] : 0.0f);
      r[2] = f32_to_bf16(m[2] ? w0[2] : 0.0f);
      r[3] = f32_to_bf16(m[3] ? w0[3] : 0.0f);
      r[4] = f32_to_bf16(m[4] ? w1[0] : 0.0f);
      r[5] = f32_to_bf16(m[5] ? w1[1] : 0.0f);
      r[6] = f32_to_bf16(m[6] ? w1[2] : 0.0f);
      r[7] = f32_to_bf16(m[7] ? w1[3] : 0.0f);
      *(ushort8*)(wb + i) = r;
    }
  }
}

// ---------------------------------------------------------------------------
// Mask detection for the fallback path only.
// ---------------------------------------------------------------------------
__global__ void detect_mask_kernel(const unsigned char* __restrict__ m, int* __restrict__ flag) {
  int found = 0;
  const int total = 1 << 20;  // scan first 4 MiB
  for (int p = blockIdx.x * blockDim.x + threadIdx.x; p < total;
       p += gridDim.x * blockDim.x)
    found |= (m[4 * p + 1] != 0);
  if (__any(found) && (threadIdx.x & 63) == 0) atomicOr(flag, 1);
}

// ---------------------------------------------------------------------------
// 8-phase 256x256 GEMM helpers (R6, unchanged)
// ---------------------------------------------------------------------------

__device__ __forceinline__ void gload16(const unsigned short* g, char* l) {
  __builtin_amdgcn_global_load_lds((const __attribute__((address_space(1))) void*)g,
                                   (__attribute__((address_space(3))) void*)l, 16, 0, 0);
}

// Stage one 128x64 half-tile (region 16 KiB): 2x global_load_lds(16B)/thread.
__device__ __forceinline__ void stage_half(const unsigned short* g0, char* region, int l0) {
  gload16(g0, region + l0);
  gload16(g0 + 8 * Kdim, region + l0 + 1024);
}

// A fragment loads: baseA already includes buffer + wm half.
// Read chunk = ((s<<2)|kg) ^ (row&7); row&7 == lane&7 for all our rows.
template <int MI0>
__device__ __forceinline__ void load_a(short8 (&a)[4][2], const char* baseA,
                                       int arow, int kg, int w7) {
#pragma unroll
  for (int mi = 0; mi < 4; ++mi) {
    const char* rowp = baseA + ((MI0 + mi) * 16 + arow) * 128;
#pragma unroll
    for (int s = 0; s < 2; ++s)
      a[mi][s] = *(const short8*)(rowp + (((s << 2) | kg) ^ w7) * 16);
  }
}

// B fragment loads: baseB already includes buffer + wnh half.
template <int NI0>
__device__ __forceinline__ void load_b(short8 (&b)[4][2], const char* baseB,
                                       int brow, int kg, int w7) {
#pragma unroll
  for (int ni = 0; ni < 2; ++ni) {
    const char* rowp = baseB + (brow + (NI0 + ni) * 16) * 128;
#pragma unroll
    for (int s = 0; s < 2; ++s)
      b[NI0 + ni][s] = *(const short8*)(rowp + (((s << 2) | kg) ^ w7) * 16);
  }
}

// One C-quadrant x K=64: 16 MFMA (4 mi x 2 ni x 2 k-halves)
template <int MIB, int NIB>
__device__ __forceinline__ void mfma_quad(f32x4 (&acc)[8][4], const short8 (&a)[4][2],
                                          const short8 (&b)[4][2]) {
#pragma unroll
  for (int s = 0; s < 2; ++s)
#pragma unroll
    for (int mi = 0; mi < 4; ++mi)
#pragma unroll
      for (int ni = 0; ni < 2; ++ni)
        acc[MIB + mi][NIB + ni] = __builtin_amdgcn_mfma_f32_16x16x32_bf16(
            a[mi][s], b[NIB + ni][s], acc[MIB + mi][NIB + ni], 0, 0, 0);
}

__device__ __forceinline__ void phase_pre() {
  __builtin_amdgcn_s_barrier();
  __builtin_amdgcn_s_setprio(1);
}

__device__ __forceinline__ void phase_post() {
  __builtin_amdgcn_s_setprio(0);
  __builtin_amdgcn_s_barrier();
}

__device__ __forceinline__ void phase_post_vm() {
  __builtin_amdgcn_s_setprio(0);
  asm volatile("s_waitcnt vmcnt(8)" ::: "memory");  // counted: 4 half-tiles in flight
  __builtin_amdgcn_s_barrier();
}

// ---------------------------------------------------------------------------
// bf16 MFMA GEMM, B^T form: O[m][n] = sum_k X[m][k]*W[n][k].  (R6, unchanged)
// ---------------------------------------------------------------------------
__global__ __launch_bounds__(512, 2) void gemm_bt_kernel(const unsigned short* __restrict__ X,
                                                         const unsigned short* __restrict__ W,
                                                         float* __restrict__ O) {
  __shared__ __align__(16) char lds[163840];
  char* sA = lds;            // [3 bufs][2 halves][16384]
  char* sB = lds + 98304;    // [2 bufs][2 halves][16384]

  const int tid = threadIdx.x;
  const int lane = tid & 63;
  const int wave = tid >> 6;
  const int wm = wave >> 2;        // 0..1 : M half (rows wm*128..+128)
  const int wn = wave & 3;         // 0..3 : N strip (cols wn*64..+64)
  const int wnh = wn >> 1;         // which B half this wave reads

  // Bijective XCD swizzle: 512 blocks, 8 XCDs -> 64 contiguous ids per XCD.
  const int bid = blockIdx.x;
  const int id = (bid & 7) * 64 + (bid >> 3);
  const int tm = id >> 4;          // 0..31
  const int tn = id & 15;          // 0..15
  const int row0 = tm * BM;
  const int col0 = tn * BN;

  // staging per-thread constants
  const int r0 = wave * 16 + (lane >> 3);             // row within half (j=0)
  const int gcol = ((lane & 7) ^ (lane >> 3)) * 8;    // pre-swizzled source col
  const int l0 = wave * 2048 + lane * 16;             // linear LDS byte offset

  // per-thread global staging bases (advance by k elems per tile)
  const unsigned short* gA0 = X + (size_t)(row0 + r0) * Kdim + gcol;   // A rows 0-127
  const unsigned short* gA1 = gA0 + (size_t)128 * Kdim;                // A rows 128-255
  const unsigned short* gB0 = W + (size_t)(col0 + r0) * Kdim + gcol;   // B rows 0-127
  const unsigned short* gB1 = gB0 + (size_t)128 * Kdim;                // B rows 128-255

  // ds_read per-thread constants
  const int arow = lane & 15;
  const int kg = lane >> 4;        // 0..3
  const int w7 = lane & 7;         // == row&7 for every row we read
  const int brow = (wn & 1) * 64 + arow;

  // B read bases (fixed: even tiles buf0, odd tiles buf1)
  const char* pBe = sB + wnh * 16384;
  const char* pBo = sB + 32768 + wnh * 16384;

  f32x4 acc[8][4];
#pragma unroll
  for (int i = 0; i < 8; ++i)
#pragma unroll
    for (int j = 0; j < 4; ++j)
#pragma unroll
      for (int r = 0; r < 4; ++r) acc[i][j][r] = 0.f;

  short8 a[4][2], b[4][2];

  // Prologue: tile 0 -> Abuf0/Bbuf0, tile 1 -> Abuf1/Bbuf1 (16 loads/thread)
  stage_half(gA0,      sA + 0,     l0);
  stage_half(gA1,      sA + 16384, l0);
  stage_half(gB0,      sB + 0,     l0);
  stage_half(gB1,      sB + 16384, l0);
  stage_half(gA0 + BK, sA + 32768, l0);
  stage_half(gA1 + BK, sA + 49152, l0);
  stage_half(gB0 + BK, sB + 32768, l0);
  stage_half(gB1 + BK, sB + 49152, l0);
  asm volatile("s_waitcnt vmcnt(8)" ::: "memory");  // tile 0 landed; tile 1 in flight
  __builtin_amdgcn_s_barrier();

  int ra = 0;  // A buffer of tile 2*it; rb=(ra+1)%3 tile 2it+1; ba=(ra+2)%3; bb=ra
#pragma unroll 1
  for (int it = 0; it < NT / 2; ++it) {
    const int rb = (ra == 2) ? 0 : ra + 1;
    const int ba = (rb == 2) ? 0 : rb + 1;
    const int bb = ra;
    const int k2 = ((2 * it + 2) & (NT - 1)) * BK;  // wrapped tail: staged, never read
    const int k3 = ((2 * it + 3) & (NT - 1)) * BK;
    const char* pAr0 = sA + (ra * 2 + wm) * 16384;
    const char* pAr1 = sA + (rb * 2 + wm) * 16384;
    char* pAs0 = sA + ba * 32768;
    char* pAs1 = sA + bb * 32768;

    // ================= tile 2*it (Abuf ra, Bbuf0) =================
    // P1
    load_a<0>(a, pAr0, arow, kg, w7);
    load_b<0>(b, pBe, brow, kg, w7);
    stage_half(gA0 + k2, pAs0, l0);              // A(t+2).h0 -> ba (free since prev P7)
    phase_pre(); mfma_quad<0, 0>(acc, a, b); phase_post();
    // P2
    load_b<2>(b, pBe, brow, kg, w7);
    stage_half(gA1 + k2, pAs0 + 16384, l0);      // A(t+2).h1
    phase_pre(); mfma_quad<0, 2>(acc, a, b); phase_post();
    // P3
    load_a<4>(a, pAr0, arow, kg, w7);
    stage_half(gB0 + k2, sB + 0, l0);            // B(t+2).h0 -> Bbuf0 (read done P2)
    phase_pre(); mfma_quad<4, 0>(acc, a, b); phase_post();
    // P4
    stage_half(gB1 + k2, sB + 16384, l0);        // B(t+2).h1
    phase_pre(); mfma_quad<4, 2>(acc, a, b); phase_post_vm();  // tile 2it+1 landed

    // ================= tile 2*it+1 (Abuf rb, Bbuf1) =================
    // P5
    load_a<0>(a, pAr1, arow, kg, w7);
    load_b<0>(b, pBo, brow, kg, w7);
    stage_half(gA0 + k3, pAs1, l0);              // A(t+3).h0 -> bb=ra (read done P3)
    phase_pre(); mfma_quad<0, 0>(acc, a, b); phase_post();
    // P6
    load_b<2>(b, pBo, brow, kg, w7);
    stage_half(gA1 + k3, pAs1 + 16384, l0);      // A(t+3).h1
    phase_pre(); mfma_quad<0, 2>(acc, a, b); phase_post();
    // P7
    load_a<4>(a, pAr1, arow, kg, w7);
    stage_half(gB0 + k3, sB + 32768, l0);        // B(t+3).h0 -> Bbuf1 (read done P6)
    phase_pre(); mfma_quad<4, 0>(acc, a, b); phase_post();
    // P8
    stage_half(gB1 + k3, sB + 49152, l0);        // B(t+3).h1
    phase_pre(); mfma_quad<4, 2>(acc, a, b); phase_post_vm();  // tile 2it+2 landed

    ra = ba;
  }

  // Epilogue: C/D row = (lane>>4)*4 + reg, col = lane&15
  const int orow0 = row0 + wm * 128 + kg * 4;
  const int ocol0 = col0 + wn * 64 + arow;
#pragma unroll
  for (int mi = 0; mi < 8; ++mi)
#pragma unroll
    for (int ni = 0; ni < 4; ++ni)
#pragma unroll
      for (int r = 0; r < 4; ++r)
        O[(size_t)(orow0 + mi * 16 + r) * Ndim + ocol0 + ni * 16] = acc[mi][ni][r];
}

// ---------------------------------------------------------------------------
// Fallback (only if ws too small for bf16 staging): fp32 LDS-tiled GEMM.
// ---------------------------------------------------------------------------
__global__ void gemm_fallback_kernel(const float* __restrict__ X, const float* __restrict__ Wt,
                                     const unsigned char* __restrict__ mraw,
                                     const int* __restrict__ flag, float* __restrict__ O) {
  __shared__ float sX[16][17];
  __shared__ float sW[16][17];
  const int tx = threadIdx.x & 15;
  const int ty = threadIdx.x >> 4;
  const long row = blockIdx.y * 16 + ty;
  const long colblock = blockIdx.x * 16;
  const int byteLayout = *flag;
  float acc = 0.f;
  for (int k0 = 0; k0 < Kdim; k0 += 16) {
    sX[ty][tx] = X[row * Kdim + k0 + tx];
    const long wi = (colblock + ty) * (long)Kdim + k0 + tx;
    const int mv = byteLayout ? (mraw[wi] != 0) : (((const int*)mraw)[wi] != 0);
    sW[ty][tx] = mv ? Wt[wi] : 0.f;
    __syncthreads();
#pragma unroll
    for (int k = 0; k < 16; ++k) acc += sX[ty][k] * sW[tx][k];
    __syncthreads();
  }
  O[row * Ndim + colblock + tx] = acc;
}

extern "C" void kernel_launch(void* const* d_in, const int* in_sizes, int n_in,
                              void* d_out, int out_size, void* d_ws, size_t ws_size,
                              hipStream_t stream) {
  const float* x = (const float*)d_in[0];               // [8192, 4096] fp32
  const float* w = (const float*)d_in[1];               // [4096, 4096] fp32
  const unsigned char* mask = (const unsigned char*)d_in[2];  // bool (layout sniffed)
  float* out = (float*)d_out;                           // [8192, 4096] fp32

  const size_t xb_off = 0;
  const size_t wb_off = (size_t)Mdim * Kdim * 2;             // 67,108,864
  const size_t needed = wb_off + (size_t)Ndim * Kdim * 2;    // 100,663,296

  if (ws_size >= needed) {
    unsigned short* xb = (unsigned short*)((char*)d_ws + xb_off);
    unsigned short* wb = (unsigned short*)((char*)d_ws + wb_off);
    prep_kernel<<<2048, 256, 0, stream>>>(x, w, mask, xb, wb);
    gemm_bt_kernel<<<(Mdim / BM) * (Ndim / BN), 512, 0, stream>>>(xb, wb, out);
  } else {
    int* flag = (int*)d_ws;
    hipMemsetAsync(flag, 0, sizeof(int), stream);
    detect_mask_kernel<<<64, 256, 0, stream>>>(mask, flag);
    dim3 grid(Ndim / 16, Mdim / 16);
    gemm_fallback_kernel<<<grid, 256, 0, stream>>>(x, w, mask, flag, out);
  }
}